// Round 4
// baseline (399.879 us; speedup 1.0000x reference)
//
#include <hip/hip_runtime.h>
#include <cstddef>

#define BATCH 4
#define SEQ   4096
#define DIM   2048
#define EPSF  1e-5f
#define TCH   8
#define CPB   (SEQ / TCH)            // 512 chunks per batch
#define NCHUNK (BATCH * CPB)         // 2048 blocks

#define F_AGG 0x40000000u
#define F_INC 0x80000000u
#define CMASK 0xFFFFu

__device__ __forceinline__ float wave_sum(float v) {
#pragma unroll
    for (int off = 32; off > 0; off >>= 1)
        v += __shfl_down(v, off, 64);
    return v;
}
__device__ __forceinline__ int wave_sum_i(int v) {
#pragma unroll
    for (int off = 32; off > 0; off >>= 1)
        v += __shfl_down(v, off, 64);
    return v;
}

// Single-pass fused kernel: rmsnorm -> causal dw-conv(W=4) -> silu -> (p1-p0)
// dot -> sign  (gate>0.5 <=> logit diff>0), then decoupled-lookback prefix to
// get this chunk's global exclusive selected-count, then scatter the selected
// x rows DIRECTLY to their final compacted destinations. Ticket-based chunk
// assignment: a block looking back at ticket < mine is guaranteed resident or
// finished (tickets are taken in dispatch order) -> no deadlock. Status words
// are device-scope atomics (cross-XCD coherent).
__global__ __launch_bounds__(256, 2) void compact_kernel(
    const float* __restrict__ x, const float* __restrict__ nw,
    const float* __restrict__ cw, const float* __restrict__ pw,
    unsigned* __restrict__ status, unsigned* __restrict__ ticket,
    int* __restrict__ nsel, float* __restrict__ out)
{
    __shared__ float lds_ss[3][4][4];   // [slot(2=warmup)][tok][wave]
    __shared__ float lds_acc[8][4];     // write-once per (token, wave)
    __shared__ int   lds_excl;
    __shared__ unsigned lds_ch;

    const int t = threadIdx.x, lane = t & 63, wid = t >> 6;
    if (t == 0) lds_ch = atomicAdd(ticket, 1u);
    __syncthreads();                                   // barrier 0
    const int ch = (int)lds_ch;
    const int b  = ch & 3;        // chain predecessor (b,c-1) has ticket ch-4
    const int c  = ch >> 2;
    const int s0 = c * TCH;
    const int d0 = 4 * t, d1 = d0 + 1024;

    // conv*norm folded (cwn), projection diff (pd)
    float cwn[8][4], pd[8];
    {
        float4 n0 = *(const float4*)(nw + d0);
        float4 n1 = *(const float4*)(nw + d1);
        float nv[8] = {n0.x, n0.y, n0.z, n0.w, n1.x, n1.y, n1.z, n1.w};
#pragma unroll
        for (int i = 0; i < 8; ++i) {
            const int d = (i < 4) ? (d0 + i) : (d1 + i - 4);
            float4 c4 = *(const float4*)(cw + 4 * d);
            cwn[i][0] = c4.x * nv[i]; cwn[i][1] = c4.y * nv[i];
            cwn[i][2] = c4.z * nv[i]; cwn[i][3] = c4.w * nv[i];
        }
        float4 a0 = *(const float4*)(pw + d0);
        float4 a1 = *(const float4*)(pw + d1);
        float4 b0 = *(const float4*)(pw + DIM + d0);
        float4 b1 = *(const float4*)(pw + DIM + d1);
        pd[0] = b0.x - a0.x; pd[1] = b0.y - a0.y; pd[2] = b0.z - a0.z; pd[3] = b0.w - a0.w;
        pd[4] = b1.x - a1.x; pd[5] = b1.y - a1.y; pd[6] = b1.z - a1.z; pd[7] = b1.w - a1.w;
    }

    const float* xb = x + (size_t)b * SEQ * DIM;
    float h1[8], h2[8], h3[8];   // normalized rows s-1, s-2, s-3

    // ---- warm-up: tokens s0-3..s0-1 ----
    {
        float wv[3][8];
#pragma unroll
        for (int w = 0; w < 3; ++w) {
            const int s = s0 - 3 + w;
            if (s >= 0) {
                float4 a = *(const float4*)(xb + (size_t)s * DIM + d0);
                float4 cc = *(const float4*)(xb + (size_t)s * DIM + d1);
                wv[w][0]=a.x; wv[w][1]=a.y; wv[w][2]=a.z; wv[w][3]=a.w;
                wv[w][4]=cc.x; wv[w][5]=cc.y; wv[w][6]=cc.z; wv[w][7]=cc.w;
            } else {
#pragma unroll
                for (int i = 0; i < 8; ++i) wv[w][i] = 0.f;
            }
            float ss = 0.f;
#pragma unroll
            for (int i = 0; i < 8; ++i) ss += wv[w][i] * wv[w][i];
            ss = wave_sum(ss);
            if (lane == 0) lds_ss[2][w][wid] = ss;
        }
        __syncthreads();                               // barrier 1
#pragma unroll
        for (int w = 0; w < 3; ++w) {
            const float sum4 = lds_ss[2][w][0] + lds_ss[2][w][1]
                             + lds_ss[2][w][2] + lds_ss[2][w][3];
            const float rstd = 1.0f / sqrtf(sum4 * (1.0f / DIM) + EPSF);
            float* h = (w == 0) ? h3 : (w == 1) ? h2 : h1;
#pragma unroll
            for (int i = 0; i < 8; ++i) h[i] = wv[w][i] * rstd;
        }
    }

    // ---- main: 2 groups of 4 tokens ----
#pragma unroll
    for (int g = 0; g < 2; ++g) {
        float xv[4][8];
#pragma unroll
        for (int j = 0; j < 4; ++j) {
            const int s = s0 + 4 * g + j;
            float4 a = *(const float4*)(xb + (size_t)s * DIM + d0);
            float4 cc = *(const float4*)(xb + (size_t)s * DIM + d1);
            xv[j][0]=a.x; xv[j][1]=a.y; xv[j][2]=a.z; xv[j][3]=a.w;
            xv[j][4]=cc.x; xv[j][5]=cc.y; xv[j][6]=cc.z; xv[j][7]=cc.w;
        }
#pragma unroll
        for (int j = 0; j < 4; ++j) {
            float ss = 0.f;
#pragma unroll
            for (int i = 0; i < 8; ++i) ss += xv[j][i] * xv[j][i];
            ss = wave_sum(ss);
            if (lane == 0) lds_ss[g][j][wid] = ss;
        }
        __syncthreads();                               // barriers 2,3
#pragma unroll
        for (int j = 0; j < 4; ++j) {
            const float sum4 = lds_ss[g][j][0] + lds_ss[g][j][1]
                             + lds_ss[g][j][2] + lds_ss[g][j][3];
            const float rstd = 1.0f / sqrtf(sum4 * (1.0f / DIM) + EPSF);
            float acc = 0.f;
#pragma unroll
            for (int i = 0; i < 8; ++i) {
                const float hc = xv[j][i] * rstd;
                const float y = cwn[i][0] * h3[i] + cwn[i][1] * h2[i]
                              + cwn[i][2] * h1[i] + cwn[i][3] * hc;
                const float sig = 1.0f / (1.0f + __expf(-y));
                acc += (y * sig) * pd[i];
                h3[i] = h2[i]; h2[i] = h1[i]; h1[i] = hc;
            }
            acc = wave_sum(acc);
            if (lane == 0) lds_acc[4 * g + j][wid] = acc;
        }
    }
    __syncthreads();                                   // barrier 4

    // ---- masks + local prefix (all threads, redundantly — cheap) ----
    int m[8], pfx[8], agg = 0;
#pragma unroll
    for (int j = 0; j < 8; ++j) {
        const float a = lds_acc[j][0] + lds_acc[j][1]
                      + lds_acc[j][2] + lds_acc[j][3];
        m[j] = (a > 0.f) ? 1 : 0;
        pfx[j] = agg;
        agg += m[j];
    }

    // ---- publish aggregate, decoupled lookback (wave 0) ----
    if (t == 0)
        __hip_atomic_store(&status[ch], F_AGG | (unsigned)agg,
                           __ATOMIC_RELEASE, __HIP_MEMORY_SCOPE_AGENT);
    if (wid == 0) {
        int excl = 0;
        int look = c - 1;
        while (look >= 0) {
            const int pos = look - lane;
            unsigned st = F_INC;   // pos<0: synthetic inclusive of 0
            if (pos >= 0)
                st = __hip_atomic_load(&status[(pos << 2) | b],
                                       __ATOMIC_RELAXED, __HIP_MEMORY_SCOPE_AGENT);
            const unsigned long long mi = __ballot((st & F_INC) != 0);
            const unsigned long long ma = __ballot((st & (F_AGG | F_INC)) != 0);
            if (mi) {
                const int L = (int)(__ffsll((long long)mi) - 1);
                if (L == 0 || ((~ma) & ((1ULL << L) - 1)) == 0) {
                    // lanes<L: aggregates; lane L: inclusive; sum = excl prefix
                    int cnt = (lane <= L) ? (int)(st & CMASK) : 0;
                    excl += wave_sum_i(cnt);
                    break;
                }
            } else if (~ma == 0ULL) {
                excl += wave_sum_i((int)(st & CMASK));
                look -= 64;
                continue;
            }
            __builtin_amdgcn_s_sleep(2);
        }
        if (lane == 0) {
            lds_excl = excl;
            __hip_atomic_store(&status[ch], F_INC | (unsigned)(excl + agg),
                               __ATOMIC_RELEASE, __HIP_MEMORY_SCOPE_AGENT);
            if (c == CPB - 1) nsel[b] = excl + agg;
        }
    }
    __syncthreads();                                   // barrier 5
    const int excl = lds_excl;

    // ---- scatter selected rows to final destinations (re-read hits L2/L3) --
#pragma unroll
    for (int j = 0; j < 8; ++j) {
        if (m[j]) {
            const float* src = xb + (size_t)(s0 + j) * DIM;
            float* o = out + ((size_t)b * SEQ + (excl + pfx[j])) * DIM;
            *(float4*)(o + d0) = *(const float4*)(src + d0);
            *(float4*)(o + d1) = *(const float4*)(src + d1);
        }
    }
}

// Zero-fill rows [nsel[b], S): with compact_kernel's writes to [0,nsel), every
// output element is written exactly once per call (d_out is poisoned 0xAA).
__global__ __launch_bounds__(256) void tail_zero_kernel(
    const int* __restrict__ nsel, float* __restrict__ out)
{
    const int b = blockIdx.x / SEQ;
    const int r = blockIdx.x - b * SEQ;
    if (r < nsel[b]) return;
    float* o = out + ((size_t)b * SEQ + r) * DIM;
    const float4 z = make_float4(0.f, 0.f, 0.f, 0.f);
    *(float4*)(o + 4 * threadIdx.x)        = z;
    *(float4*)(o + 4 * threadIdx.x + 1024) = z;
}

extern "C" void kernel_launch(void* const* d_in, const int* in_sizes, int n_in,
                              void* d_out, int out_size, void* d_ws, size_t ws_size,
                              hipStream_t stream) {
    const float* x  = (const float*)d_in[0];   // [B,S,D]
    const float* nw = (const float*)d_in[1];   // [D]
    const float* cw = (const float*)d_in[2];   // [D,4]
    const float* pw = (const float*)d_in[3];   // [2,D]
    float* out = (float*)d_out;                // [B,S,D]

    unsigned* status = (unsigned*)d_ws;        // NCHUNK words
    unsigned* ticket = status + NCHUNK;        // 1 word
    int*      nsel   = (int*)(status + NCHUNK + 4);  // 4 words

    // status=0 (invalid), ticket=0, nsel=0 — 8.2 KB, capture-safe stream op
    hipMemsetAsync(d_ws, 0, (NCHUNK + 8) * sizeof(unsigned), stream);
    compact_kernel<<<NCHUNK, 256, 0, stream>>>(x, nw, cw, pw, status, ticket, nsel, out);
    tail_zero_kernel<<<BATCH * SEQ, 256, 0, stream>>>(nsel, out);
}